// Round 11
// baseline (160.190 us; speedup 1.0000x reference)
//
#include <hip/hip_runtime.h>

#define N_NODES 50000
#define N_EDGES 800000
#define NBKT 196          // dest buckets of 256 nodes
#define BCAP 6144         // staging capacity per bucket (mean 4096 + 32 sigma)
#define UTS 136           // LDS tile row stride (halves); breaks the stride-128 16-way conflict

typedef __attribute__((ext_vector_type(4))) float floatx4;
typedef __attribute__((ext_vector_type(8))) _Float16 half8;
typedef __attribute__((ext_vector_type(4))) _Float16 half4;

// ---- workspace layout (bytes) ----
#define O_PTR   0UL          // int[N] (edge-only CSR starts)
#define O_GF    200192UL     // int[NBKT]
#define O_DINV  201472UL     // float[N]
#define O_ESRC  401664UL     // int[N_EDGES] 3.2MB
#define O_W1    3801856UL    // f16[128*128] (transposed [n][k])
#define O_W2    3834624UL    // f16[64*128]  (transposed [n][k])
#define O_STG   3851008UL    // u32 staging[NBKT*BCAP] = 4.8MB
#define O_H16   16651008UL   // f16[N*128] dinv-prescaled h
// end: 29451008 bytes (<= 29.9MB proven footprint)

// Pass A: coarse-bin edges by dest>>8 into per-bucket staging runs.
// Index width (int32 vs int64) probed per-block from the first 64 odd words.
__global__ __launch_bounds__(256) void k_binA(const int* __restrict__ ei,
                                              int* __restrict__ gfill,
                                              unsigned* __restrict__ staging) {
    __shared__ int cnt[NBKT];
    __shared__ int gbase[NBKT];
    __shared__ int s_i64;
    int t = threadIdx.x;
    if (t < 64) {                                  // wave 0: int64 probe
        unsigned w = ((const unsigned*)ei)[2 * t + 1];
        unsigned long long m = __ballot(w == 0u);
        if (t == 0) s_i64 = (__popcll(m) >= 60) ? 1 : 0;
    }
    for (int i = t; i < NBKT; i += 256) cnt[i] = 0;
    __syncthreads();
    bool i64 = s_i64 != 0;
    int e0 = blockIdx.x * 4096 + t * 16;           // 16 edges per thread
    int sv[16], dvv[16];
    if (i64) {
        const int4* ps = (const int4*)(ei) + (e0 >> 1);
        const int4* pd = (const int4*)(ei + 2 * (size_t)N_EDGES) + (e0 >> 1);
#pragma unroll
        for (int g = 0; g < 8; ++g) {
            if (e0 + 2 * g < N_EDGES) {
                int4 s4 = ps[g], d4 = pd[g];
                sv[2 * g] = s4.x; sv[2 * g + 1] = s4.z;
                dvv[2 * g] = d4.x; dvv[2 * g + 1] = d4.z;
            } else { dvv[2 * g] = -1; dvv[2 * g + 1] = -1; }
        }
    } else {
        const int4* ps = (const int4*)(ei) + (e0 >> 2);
        const int4* pd = (const int4*)(ei + (size_t)N_EDGES) + (e0 >> 2);
#pragma unroll
        for (int g = 0; g < 4; ++g) {
            if (e0 + 4 * g < N_EDGES) {
                int4 s4 = ps[g], d4 = pd[g];
                sv[4 * g] = s4.x; sv[4 * g + 1] = s4.y; sv[4 * g + 2] = s4.z; sv[4 * g + 3] = s4.w;
                dvv[4 * g] = d4.x; dvv[4 * g + 1] = d4.y; dvv[4 * g + 2] = d4.z; dvv[4 * g + 3] = d4.w;
            } else { dvv[4 * g] = -1; dvv[4 * g + 1] = -1; dvv[4 * g + 2] = -1; dvv[4 * g + 3] = -1; }
        }
    }
    unsigned pk[16]; int rk[16]; short bk[16];
#pragma unroll
    for (int j = 0; j < 16; ++j) {
        int d = dvv[j];
        if (d >= 0 && e0 + j < N_EDGES) {
            int b = d >> 8;
            bk[j] = (short)b;
            pk[j] = (unsigned)sv[j] | ((unsigned)(d & 255) << 16);
            rk[j] = atomicAdd(&cnt[b], 1);
        } else bk[j] = -1;
    }
    __syncthreads();
    for (int i = t; i < NBKT; i += 256)
        gbase[i] = atomicAdd(&gfill[i], cnt[i]);
    __syncthreads();
#pragma unroll
    for (int j = 0; j < 16; ++j) {
        if (bk[j] >= 0) {
            int pos = gbase[bk[j]] + rk[j];
            if (pos < BCAP) staging[(size_t)bk[j] * BCAP + pos] = pk[j];
        }
    }
}

// Pass B: per bucket -> edge-only CSR, dinv, dinv-prescaled h16.
// Blocks 0..95 additionally transpose one 256-elem weight chunk to f16.
__global__ __launch_bounds__(256) void k_binB(const unsigned* __restrict__ staging,
                                              const int* __restrict__ gfill,
                                              const float* __restrict__ h,
                                              const float* __restrict__ Wg,
                                              const float* __restrict__ Wf,
                                              int* __restrict__ ptr,
                                              float* __restrict__ dinv,
                                              _Float16* __restrict__ h16,
                                              _Float16* __restrict__ W1,
                                              _Float16* __restrict__ W2,
                                              int* __restrict__ esrc) {
    __shared__ unsigned se[BCAP];
    __shared__ int lcnt[256];
    __shared__ int lscan[256];
    __shared__ int cur[256];
    __shared__ float sdinv[256];
    __shared__ int s_cb;
    int b = blockIdx.x, t = threadIdx.x;
    if (b < 64) {
        int i = b * 256 + t;                       // W1: 16384 elems
        int n = i >> 7, k = i & 127;
        W1[i] = (_Float16)Wg[k * 128 + n];
    } else if (b < 96) {
        int i = (b - 64) * 256 + t;                // W2: 8192 elems
        int n = i >> 7, k = i & 127;
        W2[i] = (_Float16)Wf[k * 64 + n];
    }
    int nbase = b * 256;
    int nn = min(256, N_NODES - nbase);
    int cnt = min(gfill[b], BCAP);
    if (t < 64) {                                  // edge-CSR base: sum_{i<b} edges_i
        int acc = 0;
        for (int i = t; i < b; i += 64) acc += min(gfill[i], BCAP);
#pragma unroll
        for (int off = 32; off > 0; off >>= 1) acc += __shfl_down(acc, off);
        if (t == 0) s_cb = acc;
    }
    lcnt[t] = 0;
    __syncthreads();
    int cb = s_cb;
    const unsigned* st = staging + (size_t)b * BCAP;
    for (int i = t; i < cnt; i += 256) {
        unsigned p = st[i];
        se[i] = p;
        atomicAdd(&lcnt[p >> 16], 1);
    }
    __syncthreads();
    int v = lcnt[t];
    lscan[t] = v;
    __syncthreads();
    for (int off = 1; off < 256; off <<= 1) {
        int x = (t >= off) ? lscan[t - off] : 0;
        __syncthreads(); lscan[t] += x; __syncthreads();
    }
    int segstart = cb + (lscan[t] - v);
    float dv = rsqrtf((float)(v + 1));             // +1 = self-loop (analytic in k_aggF)
    if (t < nn) {
        int node = nbase + t;
        ptr[node] = segstart;
        dinv[node] = dv;
        sdinv[t] = dv;
        cur[t] = segstart;
    }
    __syncthreads();
    for (int i = t; i < cnt; i += 256) {           // single-pass scatter
        unsigned p = se[i];
        int pos = atomicAdd(&cur[p >> 16], 1);
        esrc[pos] = (int)(p & 0xffffu);
    }
    int half = t >> 7;
    int col = t & 127;
    for (int r = half; r < nn; r += 2) {           // h16 = f16(h * dinv), coalesced
        int node = nbase + r;
        h16[(size_t)node * 128 + col] = (_Float16)(h[(size_t)node * 128 + col] * sdinv[r]);
    }
}

// Fused aggregate + double GEMM. Block = 16 consecutive nodes (grid 3125).
// Gather: 8B/lane half4, 32 lanes per row -> 2 edges per wave-load, 8-deep
// (64 cache lines in flight per wave, 2x round-10). VGPR kept <=64 via
// launch_bounds(256,8) — round-9's 16B/lane variant hit VGPR 68 and halved
// occupancy (57%->27%, +30us); this keeps temps at 16 VGPRs.
__global__ __launch_bounds__(256, 8) void k_aggF(const _Float16* __restrict__ h16,
                                                 const int* __restrict__ ptr,
                                                 const int* __restrict__ esrc,
                                                 const float* __restrict__ dinv,
                                                 const _Float16* __restrict__ W1,
                                                 const _Float16* __restrict__ W2,
                                                 const float* __restrict__ bg,
                                                 const float* __restrict__ bfc,
                                                 float* __restrict__ out) {
    __shared__ _Float16 ut[16 * UTS];
    __shared__ _Float16 z[16 * UTS];
    int wave = threadIdx.x >> 6;
    int lane = threadIdx.x & 63;
    int nb = blockIdx.x * 16;
    int e2 = lane >> 5;                    // which edge of a pair
    int c4 = (lane & 31) * 4;              // dim offset (halves); 32 lanes = full 256B row
    for (int q = 0; q < 4; ++q) {
        int node = nb + wave * 4 + q;
        int p0 = ptr[node];
        int p1 = (node + 1 < N_NODES) ? ptr[node + 1] : N_EDGES;
        float a0, a1, a2, a3;
        if (e2 == 0) {                     // self-loop seeds group 0
            half4 us = *(const half4*)(h16 + (size_t)node * 128 + c4);
            a0 = (float)us[0]; a1 = (float)us[1]; a2 = (float)us[2]; a3 = (float)us[3];
        } else { a0 = a1 = a2 = a3 = 0.f; }
        for (int base = p0; base < p1; base += 64) {
            int cnt = p1 - base; if (cnt > 64) cnt = 64;
            int idx = 0;
            if (lane < cnt) idx = esrc[base + lane];
            int j = 0;
            for (; j + 16 <= cnt; j += 16) {   // 8 pair-loads = 16 edges in flight
                int r0 = __shfl(idx, j + 0 + e2),  r1 = __shfl(idx, j + 2 + e2);
                int r2 = __shfl(idx, j + 4 + e2),  r3 = __shfl(idx, j + 6 + e2);
                int r4 = __shfl(idx, j + 8 + e2),  r5 = __shfl(idx, j + 10 + e2);
                int r6 = __shfl(idx, j + 12 + e2), r7 = __shfl(idx, j + 14 + e2);
                half4 u0 = *(const half4*)(h16 + (size_t)r0 * 128 + c4);
                half4 u1 = *(const half4*)(h16 + (size_t)r1 * 128 + c4);
                half4 u2 = *(const half4*)(h16 + (size_t)r2 * 128 + c4);
                half4 u3 = *(const half4*)(h16 + (size_t)r3 * 128 + c4);
                half4 u4 = *(const half4*)(h16 + (size_t)r4 * 128 + c4);
                half4 u5 = *(const half4*)(h16 + (size_t)r5 * 128 + c4);
                half4 u6 = *(const half4*)(h16 + (size_t)r6 * 128 + c4);
                half4 u7 = *(const half4*)(h16 + (size_t)r7 * 128 + c4);
                a0 += (float)u0[0] + (float)u1[0] + (float)u2[0] + (float)u3[0]
                    + (float)u4[0] + (float)u5[0] + (float)u6[0] + (float)u7[0];
                a1 += (float)u0[1] + (float)u1[1] + (float)u2[1] + (float)u3[1]
                    + (float)u4[1] + (float)u5[1] + (float)u6[1] + (float)u7[1];
                a2 += (float)u0[2] + (float)u1[2] + (float)u2[2] + (float)u3[2]
                    + (float)u4[2] + (float)u5[2] + (float)u6[2] + (float)u7[2];
                a3 += (float)u0[3] + (float)u1[3] + (float)u2[3] + (float)u3[3]
                    + (float)u4[3] + (float)u5[3] + (float)u6[3] + (float)u7[3];
            }
            for (; j + 2 <= cnt; j += 2) {
                int r = __shfl(idx, j + e2);
                half4 u = *(const half4*)(h16 + (size_t)r * 128 + c4);
                a0 += (float)u[0]; a1 += (float)u[1]; a2 += (float)u[2]; a3 += (float)u[3];
            }
            if (j < cnt) {                     // odd tail: group 0 only
                int r = __shfl(idx, j);
                if (e2 == 0) {
                    half4 u = *(const half4*)(h16 + (size_t)r * 128 + c4);
                    a0 += (float)u[0]; a1 += (float)u[1]; a2 += (float)u[2]; a3 += (float)u[3];
                }
            }
        }
        a0 += __shfl_xor(a0, 32);              // fold the two edge-groups
        a1 += __shfl_xor(a1, 32);
        a2 += __shfl_xor(a2, 32);
        a3 += __shfl_xor(a3, 32);
        if (lane < 32) {
            float sc = dinv[node];
            half4 o;
            o[0] = (_Float16)(a0 * sc); o[1] = (_Float16)(a1 * sc);
            o[2] = (_Float16)(a2 * sc); o[3] = (_Float16)(a3 * sc);
            *(half4*)(ut + (wave * 4 + q) * UTS + c4) = o;
        }
    }
    __syncthreads();
    int quad = lane >> 4, l15 = lane & 15;
    half8 a[4];
#pragma unroll
    for (int kk = 0; kk < 4; ++kk)
        a[kk] = *(const half8*)(ut + l15 * UTS + kk * 32 + quad * 8);
#pragma unroll
    for (int tt = 0; tt < 2; ++tt) {               // GEMM1: wave does 2 of 8 n-tiles
        floatx4 acc = {0.f, 0.f, 0.f, 0.f};
        int n = (wave * 2 + tt) * 16 + l15;
#pragma unroll
        for (int kk = 0; kk < 4; ++kk) {
            half8 bb = *(const half8*)(W1 + n * 128 + kk * 32 + quad * 8);
            acc = __builtin_amdgcn_mfma_f32_16x16x32_f16(a[kk], bb, acc, 0, 0, 0);
        }
        float bias = bg[n];
#pragma unroll
        for (int i = 0; i < 4; ++i)
            z[(quad * 4 + i) * UTS + n] = (_Float16)fmaxf(acc[i] + bias, 0.f);
    }
    __syncthreads();
    half8 a2r[4];
#pragma unroll
    for (int kk = 0; kk < 4; ++kk)
        a2r[kk] = *(const half8*)(z + l15 * UTS + kk * 32 + quad * 8);
    {                                               // GEMM2: wave does 1 of 4 n-tiles
        floatx4 acc = {0.f, 0.f, 0.f, 0.f};
        int n = wave * 16 + l15;
#pragma unroll
        for (int kk = 0; kk < 4; ++kk) {
            half8 bb = *(const half8*)(W2 + n * 128 + kk * 32 + quad * 8);
            acc = __builtin_amdgcn_mfma_f32_16x16x32_f16(a2r[kk], bb, acc, 0, 0, 0);
        }
        float bias = bfc[n];
#pragma unroll
        for (int i = 0; i < 4; ++i)
            out[(size_t)(nb + quad * 4 + i) * 64 + n] = acc[i] + bias;
    }
}

extern "C" void kernel_launch(void* const* d_in, const int* in_sizes, int n_in,
                              void* d_out, int out_size, void* d_ws, size_t ws_size,
                              hipStream_t stream) {
    (void)in_sizes; (void)n_in; (void)out_size; (void)ws_size;
    const float* h  = (const float*)d_in[0];
    const int*   ei = (const int*)d_in[1];
    const float* Wg = (const float*)d_in[2];
    const float* bg = (const float*)d_in[3];
    const float* Wf = (const float*)d_in[4];
    const float* bf = (const float*)d_in[5];
    float* out = (float*)d_out;

    char* ws = (char*)d_ws;
    int*      ptr   = (int*)(ws + O_PTR);
    int*      gfill = (int*)(ws + O_GF);
    float*    dinv  = (float*)(ws + O_DINV);
    int*      esrc  = (int*)(ws + O_ESRC);
    _Float16* W1    = (_Float16*)(ws + O_W1);
    _Float16* W2    = (_Float16*)(ws + O_W2);
    unsigned* staging = (unsigned*)(ws + O_STG);
    _Float16* h16   = (_Float16*)(ws + O_H16);

    hipMemsetAsync(gfill, 0, NBKT * sizeof(int), stream);
    k_binA<<<NBKT, 256, 0, stream>>>(ei, gfill, staging);
    k_binB<<<NBKT, 256, 0, stream>>>(staging, gfill, h, Wg, Wf,
                                     ptr, dinv, h16, W1, W2, esrc);
    k_aggF<<<N_NODES / 16, 256, 0, stream>>>(h16, ptr, esrc, dinv,
                                             W1, W2, bg, bf, out);
}